// Round 2
// baseline (53.041 us; speedup 1.0000x reference)
//
#include <hip/hip_runtime.h>
#include <math.h>

// LocalPODLoss: out = 0.5 * (1e-6 + sqrt(ss)); ss = triangular-weighted squares
// of 16-long sliding-window sums of D = new - old along rows and cols, per
// (b,c) 32x32 tile. Only scale s=1 contributes.
//
// Fused single kernel: per-block partial -> last-block-done reduction (fixed
// order => bit-deterministic). Counter zeroed each call via hipMemsetAsync.

#define TILE_PAD 33
#define TILE_STRIDE (32 * TILE_PAD)          // 1056 floats per padded tile
#define CHUNK_TILES 4
#define TPB_TILES 8                          // tiles per block
#define BLOCK_FLOATS (TPB_TILES * 1024)      // 8192

// Per-chunk term: threads 0..127 do the 'left' term (column windows),
// threads 128..255 the 'right' term (row windows). Branch is wave-uniform.
__device__ __forceinline__ float chunk_term(const float* __restrict__ buf, int tid) {
    const int item = tid & 127;
    const int tile = item >> 5;
    const int lane = item & 31;
    float v[32];
    if (tid < 128) {
        const float* p = &buf[tile * TILE_STRIDE + lane];        // column read, stride 33
#pragma unroll
        for (int k = 0; k < 32; ++k) v[k] = p[k * TILE_PAD];
    } else {
        const float* p = &buf[tile * TILE_STRIDE + lane * TILE_PAD];  // row read
#pragma unroll
        for (int k = 0; k < 32; ++k) v[k] = p[k];
    }
    float W = 0.0f;
#pragma unroll
    for (int k = 0; k < 16; ++k) W += v[k];
    float s2 = W * W;
#pragma unroll
    for (int i = 1; i < 16; ++i) { W += v[i + 15] - v[i - 1]; s2 += W * W; }
    float wgt = (lane < 16) ? (float)(lane + 1) : (float)(31 - lane);  // triangular cnt
    return wgt * s2;
}

__global__ __launch_bounds__(256) void pod_fused(const float* __restrict__ nf,
                                                 const float* __restrict__ of,
                                                 unsigned* __restrict__ counter,
                                                 float* __restrict__ partial,
                                                 float* __restrict__ out) {
    __shared__ float ds[2][CHUNK_TILES * TILE_STRIDE];   // 2 x 16.9 KB
    const int tid = threadIdx.x;
    const size_t base = (size_t)blockIdx.x * BLOCK_FLOATS;
    const float4* nf4 = reinterpret_cast<const float4*>(nf + base);
    const float4* of4 = reinterpret_cast<const float4*>(of + base);

    // ---- chunk 0 loads (8 float4 / thread) ----
    float4 a0[4], b0[4];
#pragma unroll
    for (int it = 0; it < 4; ++it) {
        int e4 = it * 256 + tid;
        a0[it] = nf4[e4];
        b0[it] = of4[e4];
    }
    // stage chunk 0 into LDS buf0 (D = a - b)
#pragma unroll
    for (int it = 0; it < 4; ++it) {
        int e = (it * 256 + tid) * 4;                    // no row crossing (32%4==0)
        int tile = e >> 10, r = (e >> 5) & 31, c = e & 31;
        float* dst = &ds[0][tile * TILE_STRIDE + r * TILE_PAD + c];
        dst[0] = a0[it].x - b0[it].x;
        dst[1] = a0[it].y - b0[it].y;
        dst[2] = a0[it].z - b0[it].z;
        dst[3] = a0[it].w - b0[it].w;
    }
    // ---- chunk 1 loads issued; in flight during chunk-0 compute ----
    float4 a1[4], b1[4];
#pragma unroll
    for (int it = 0; it < 4; ++it) {
        int e4 = 1024 + it * 256 + tid;
        a1[it] = nf4[e4];
        b1[it] = of4[e4];
    }
    __syncthreads();

    float acc = chunk_term(&ds[0][0], tid);

    // stage chunk 1 into buf1 (independent of buf0 reads -> no sync needed first)
#pragma unroll
    for (int it = 0; it < 4; ++it) {
        int e = (it * 256 + tid) * 4;
        int tile = e >> 10, r = (e >> 5) & 31, c = e & 31;
        float* dst = &ds[1][tile * TILE_STRIDE + r * TILE_PAD + c];
        dst[0] = a1[it].x - b1[it].x;
        dst[1] = a1[it].y - b1[it].y;
        dst[2] = a1[it].z - b1[it].z;
        dst[3] = a1[it].w - b1[it].w;
    }
    __syncthreads();

    acc += chunk_term(&ds[1][0], tid);
    acc *= (1.0f / 256.0f);                              // the /w and /h squared

    // ---- deterministic block reduction ----
#pragma unroll
    for (int off = 32; off > 0; off >>= 1) acc += __shfl_down(acc, off, 64);
    __shared__ float wsum[4];
    if ((tid & 63) == 0) wsum[tid >> 6] = acc;
    __syncthreads();

    __shared__ unsigned last;
    if (tid == 0) {
        float total = (wsum[0] + wsum[1]) + (wsum[2] + wsum[3]);
        partial[blockIdx.x] = total;
        __threadfence();                                 // release: partial visible device-wide
        unsigned old = atomicAdd(counter, 1u);
        last = (old == gridDim.x - 1) ? 1u : 0u;
    }
    __syncthreads();

    if (last) {
        __threadfence();                                 // acquire: see all partials
        float s = 0.0f;
        for (unsigned i = tid; i < gridDim.x; i += 256)  // fixed order: deterministic
            s += partial[i];
        __shared__ float sh[256];
        sh[tid] = s;
        __syncthreads();
        for (int st = 128; st > 0; st >>= 1) {
            if (tid < st) sh[tid] += sh[tid + st];
            __syncthreads();
        }
        if (tid == 0) out[0] = 0.5f * (1e-6f + sqrtf(sh[0]));
    }
}

extern "C" void kernel_launch(void* const* d_in, const int* in_sizes, int n_in,
                              void* d_out, int out_size, void* d_ws, size_t ws_size,
                              hipStream_t stream) {
    const float* nf = (const float*)d_in[0];
    const float* of = (const float*)d_in[1];
    float* out = (float*)d_out;

    unsigned* counter = (unsigned*)d_ws;                 // 4 bytes
    float* partial = (float*)d_ws + 64;                  // 256-byte offset, 4 KB

    const int nblocks = in_sizes[0] / BLOCK_FLOATS;      // 8388608 / 8192 = 1024

    hipMemsetAsync(counter, 0, sizeof(unsigned), stream);
    hipLaunchKernelGGL(pod_fused, dim3(nblocks), dim3(256), 0, stream,
                       nf, of, counter, partial, out);
}

// Round 3
// 40.635 us; speedup vs baseline: 1.3053x; 1.3053x over previous
//
#include <hip/hip_runtime.h>
#include <math.h>

// LocalPODLoss: out = 0.5 * (1e-6 + sqrt(ss)); ss = triangular-weighted squares
// of 16-long sliding-window sums of D = new - old along rows and cols, per
// (b,c) 32x32 tile. Only scale s=1 contributes (s=0 has zero window positions).
//
// Single fused kernel. Cross-block combine via FIXED-POINT INT64 atomicAdd
// (associative => bit-deterministic) + ordered arrival counter. NO
// __threadfence anywhere: device-scope atomic RMWs are coherent at the
// coherence point; ordering (ss-add before counter-add) is forced by a data
// dependency through an empty asm. (Round-2 lesson: per-block __threadfence
// = L2 writeback per block = ~55us of stall on gfx950.)

#define TILE_PAD 33
#define TILE_STRIDE (32 * TILE_PAD)      // 1056 floats per padded tile
#define NTILES 8                         // tiles per block
#define BLOCK_FLOATS (NTILES * 1024)     // 8192
#define FP_SCALE 1048576.0f              // 2^20 fixed-point scale

__global__ __launch_bounds__(256) void pod_fused(const float* __restrict__ nf,
                                                 const float* __restrict__ of,
                                                 unsigned long long* __restrict__ ssAcc,
                                                 unsigned* __restrict__ counter,
                                                 float* __restrict__ out,
                                                 unsigned nblocks) {
    __shared__ float ds[NTILES * TILE_STRIDE];   // 33 KB
    const int tid = threadIdx.x;
    const size_t base = (size_t)blockIdx.x * BLOCK_FLOATS;
    const float4* nf4 = reinterpret_cast<const float4*>(nf + base);
    const float4* of4 = reinterpret_cast<const float4*>(of + base);

    // ---- load 64 KB (16 float4/thread), max MLP: all loads issued first ----
    float4 a[8], b[8];
#pragma unroll
    for (int it = 0; it < 8; ++it) a[it] = nf4[it * 256 + tid];
#pragma unroll
    for (int it = 0; it < 8; ++it) b[it] = of4[it * 256 + tid];

    // ---- stage D = a - b into padded LDS tiles ----
#pragma unroll
    for (int it = 0; it < 8; ++it) {
        int e = (it * 256 + tid) * 4;            // flat float index (32 % 4 == 0: no row crossing)
        int tile = e >> 10, r = (e >> 5) & 31, c = e & 31;
        float* dst = &ds[tile * TILE_STRIDE + r * TILE_PAD + c];
        dst[0] = a[it].x - b[it].x;
        dst[1] = a[it].y - b[it].y;
        dst[2] = a[it].z - b[it].z;
        dst[3] = a[it].w - b[it].w;
    }
    __syncthreads();

    float acc = 0.0f;

    // Phase A (left term): thread owns (tile, col); 16-window sliding sum over rows.
    {
        int tile = tid >> 5, col = tid & 31;
        const float* p = &ds[tile * TILE_STRIDE + col];
        float v[32];
#pragma unroll
        for (int r = 0; r < 32; ++r) v[r] = p[r * TILE_PAD];   // stride-33: conflict-free
        float W = 0.0f;
#pragma unroll
        for (int r = 0; r < 16; ++r) W += v[r];
        float s2 = W * W;
#pragma unroll
        for (int i = 1; i < 16; ++i) { W += v[i + 15] - v[i - 1]; s2 += W * W; }
        float wl = (col < 16) ? (float)(col + 1) : (float)(31 - col);  // triangular cnt
        acc += wl * s2;
    }

    // Phase B (right term): thread owns (tile, row); 16-window sliding sum over cols.
    {
        int tile = tid >> 5, row = tid & 31;
        const float* p = &ds[tile * TILE_STRIDE + row * TILE_PAD];
        float v[32];
#pragma unroll
        for (int c = 0; c < 32; ++c) v[c] = p[c];
        float W = 0.0f;
#pragma unroll
        for (int c = 0; c < 16; ++c) W += v[c];
        float s2 = W * W;
#pragma unroll
        for (int j = 1; j < 16; ++j) { W += v[j + 15] - v[j - 1]; s2 += W * W; }
        float wr = (row < 16) ? (float)(row + 1) : (float)(31 - row);
        acc += wr * s2;
    }

    acc *= (1.0f / 256.0f);                      // the /w and /h squared

    // ---- deterministic block reduction: wave64 shuffle + LDS combine ----
#pragma unroll
    for (int off = 32; off > 0; off >>= 1) acc += __shfl_down(acc, off, 64);
    __shared__ float wsum[4];
    if ((tid & 63) == 0) wsum[tid >> 6] = acc;
    __syncthreads();

    if (tid == 0) {
        float total = (wsum[0] + wsum[1]) + (wsum[2] + wsum[3]);
        long long q = (long long)(total * FP_SCALE);            // fixed-point, |q| < 2^45
        unsigned long long old = atomicAdd(ssAcc, (unsigned long long)q);
        // Force the counter RMW to issue only after the ss RMW returned
        // (device-coherent completion): opaque data dependency on 'old'.
        unsigned inc = 1u;
        asm volatile("" : "+v"(inc) : "v"((unsigned)old));
        unsigned done = atomicAdd(counter, inc);
        if (done == nblocks - 1u) {
            // Unique last block: all ss-adds completed (each preceded its
            // counter-add). Coherent read via RMW-with-0.
            unsigned long long v = atomicAdd(ssAcc, 0ull);
            float ss = (float)(long long)v * (1.0f / FP_SCALE);
            out[0] = 0.5f * (1e-6f + sqrtf(ss));
        }
    }
}

extern "C" void kernel_launch(void* const* d_in, const int* in_sizes, int n_in,
                              void* d_out, int out_size, void* d_ws, size_t ws_size,
                              hipStream_t stream) {
    const float* nf = (const float*)d_in[0];
    const float* of = (const float*)d_in[1];
    float* out = (float*)d_out;

    unsigned long long* ssAcc = (unsigned long long*)d_ws;   // 8 B
    unsigned* counter = (unsigned*)((char*)d_ws + 8);        // 4 B

    const unsigned nblocks = (unsigned)(in_sizes[0] / BLOCK_FLOATS);   // 1024

    hipMemsetAsync(d_ws, 0, 16, stream);
    hipLaunchKernelGGL(pod_fused, dim3(nblocks), dim3(256), 0, stream,
                       nf, of, ssAcc, counter, out, nblocks);
}

// Round 4
// 17.528 us; speedup vs baseline: 3.0260x; 2.3182x over previous
//
#include <hip/hip_runtime.h>
#include <math.h>

// LocalPODLoss: out = 0.5 * (1e-6 + sqrt(ss)); ss = triangular-weighted squares
// of 16-long sliding-window sums of D = new - old along rows and cols, per
// (b,c) 32x32 tile. Only scale s=1 contributes (s=0 has zero window positions).
//
// Structure lessons (R2/R3): NO fences (R2: +51us, per-block L2 writeback),
// NO same-address atomics / memset nodes (R3: +22us tail). Two plain kernels:
// per-block partials via plain stores, then a 1-block finalize. Deterministic
// by construction (fixed-order reductions, no atomics).

#define TILE_PAD 33
#define TILE_STRIDE (32 * TILE_PAD)      // 1056 floats per padded tile
#define NTILES 4                         // tiles per block
#define BLOCK_FLOATS (NTILES * 1024)     // 4096
#define NBLOCKS 2048

__global__ __launch_bounds__(256) void pod_partial(const float* __restrict__ nf,
                                                   const float* __restrict__ of,
                                                   float* __restrict__ partial) {
    __shared__ float ds[NTILES * TILE_STRIDE];   // 16.9 KB -> 8 blocks/CU
    const int tid = threadIdx.x;
    const size_t base = (size_t)blockIdx.x * BLOCK_FLOATS;
    const float4* nf4 = reinterpret_cast<const float4*>(nf + base);
    const float4* of4 = reinterpret_cast<const float4*>(of + base);

    // ---- all 8 loads issued upfront (max MLP), then subtract+stage ----
    float4 a[NTILES], b[NTILES];
#pragma unroll
    for (int it = 0; it < NTILES; ++it) a[it] = nf4[it * 256 + tid];
#pragma unroll
    for (int it = 0; it < NTILES; ++it) b[it] = of4[it * 256 + tid];

#pragma unroll
    for (int it = 0; it < NTILES; ++it) {
        int e = (it * 256 + tid) * 4;            // flat float index (32%4==0: no row crossing)
        int tile = e >> 10, r = (e >> 5) & 31, c = e & 31;
        float* dst = &ds[tile * TILE_STRIDE + r * TILE_PAD + c];
        dst[0] = a[it].x - b[it].x;
        dst[1] = a[it].y - b[it].y;
        dst[2] = a[it].z - b[it].z;
        dst[3] = a[it].w - b[it].w;
    }
    __syncthreads();

    // ---- split phases across waves: 4 tiles x 32 lanes = 128 items/term.
    // Waves 0-1 (tid<128): 'left' term, column windows (stride-33 reads,
    // conflict-free). Waves 2-3: 'right' term, row windows. Wave-uniform.
    const int item = tid & 127;
    const int tile = item >> 5;
    const int lane = item & 31;
    float v[32];
    if (tid < 128) {
        const float* p = &ds[tile * TILE_STRIDE + lane];
#pragma unroll
        for (int k = 0; k < 32; ++k) v[k] = p[k * TILE_PAD];
    } else {
        const float* p = &ds[tile * TILE_STRIDE + lane * TILE_PAD];
#pragma unroll
        for (int k = 0; k < 32; ++k) v[k] = p[k];
    }
    float W = 0.0f;
#pragma unroll
    for (int k = 0; k < 16; ++k) W += v[k];
    float s2 = W * W;
#pragma unroll
    for (int i = 1; i < 16; ++i) { W += v[i + 15] - v[i - 1]; s2 += W * W; }
    float wgt = (lane < 16) ? (float)(lane + 1) : (float)(31 - lane);  // triangular cnt
    float acc = wgt * s2 * (1.0f / 256.0f);      // the /w and /h squared

    // ---- deterministic block reduction: wave64 shuffle + LDS combine ----
#pragma unroll
    for (int off = 32; off > 0; off >>= 1) acc += __shfl_down(acc, off, 64);
    __shared__ float wsum[4];
    if ((tid & 63) == 0) wsum[tid >> 6] = acc;
    __syncthreads();
    if (tid == 0) partial[blockIdx.x] = (wsum[0] + wsum[1]) + (wsum[2] + wsum[3]);
}

__global__ __launch_bounds__(256) void pod_final(const float* __restrict__ partial,
                                                 float* __restrict__ out) {
    __shared__ float sh[256];
    int tid = threadIdx.x;
    float a = 0.0f;
#pragma unroll
    for (int i = 0; i < NBLOCKS / 256; ++i) a += partial[i * 256 + tid];  // fixed order
    sh[tid] = a;
    __syncthreads();
    for (int s = 128; s > 0; s >>= 1) {
        if (tid < s) sh[tid] += sh[tid + s];
        __syncthreads();
    }
    if (tid == 0) out[0] = 0.5f * (1e-6f + sqrtf(sh[0]));
}

extern "C" void kernel_launch(void* const* d_in, const int* in_sizes, int n_in,
                              void* d_out, int out_size, void* d_ws, size_t ws_size,
                              hipStream_t stream) {
    const float* nf = (const float*)d_in[0];
    const float* of = (const float*)d_in[1];
    float* out = (float*)d_out;
    float* partial = (float*)d_ws;               // 2048 floats = 8 KB

    hipLaunchKernelGGL(pod_partial, dim3(NBLOCKS), dim3(256), 0, stream, nf, of, partial);
    hipLaunchKernelGGL(pod_final, dim3(1), dim3(256), 0, stream, partial, out);
}